// Round 4
// baseline (206.421 us; speedup 1.0000x reference)
//
#include <hip/hip_runtime.h>

// CapsuleOut: B=256, O=10, R=1152, I=8, D=16, 3 routing iterations.
// SINGLE kernel (no transpose dispatch, no workspace):
//  - grid = (o, b-pair) = 1280 blocks, 384 threads, XCD-swizzled.
//  - W[o] slice streamed through LDS in 12 chunks of 96 rows (48 KB),
//    global loads fully coalesced, LDS XOR-swizzled (idx ^= row&7) so the
//    per-thread row reads (512 B stride) don't 32-way bank-conflict.
//  - Thread t owns routes r = t + 384k (k=0..2), both batches' priors in
//    registers: 96 floats. __launch_bounds__(384,2) -> VGPR cap >=170
//    under either arg interpretation (round-2/3 spills came from the
//    2nd arg being treated as blocks/CU: cap ~102, VGPR_Count=84).
//  - Routing: softmax without max-subtraction (logits bounded ~+-30),
//    DPP 16-lane reductions + 34-thread cross-group pass (round-3 scheme).

#define BB 256
#define OO 10
#define RR 1152
#define II 8
#define DD 16
#define NITER 3
#define NT 384
#define NB 2
#define CH 96                      // rows per LDS chunk
#define GRID (OO * BB / NB)        // 1280, divisible by 8
#define NGRP (NT / 16)             // 24 sixteen-lane groups

// ---- 16-lane in-register reduction: VALU-pipe only (DPP) ----
template<int CTRL>
__device__ __forceinline__ float dpp_add(float x) {
    int p = __builtin_amdgcn_update_dpp(0, __float_as_int(x), CTRL, 0xF, 0xF, true);
    return x + __int_as_float(p);
}
__device__ __forceinline__ float red16(float x) {
    x = dpp_add<0xB1>(x);    // quad_perm(1,0,3,2)
    x = dpp_add<0x4E>(x);    // quad_perm(2,3,0,1)
    x = dpp_add<0x124>(x);   // row_ror:4
    x = dpp_add<0x128>(x);   // row_ror:8
    return x;                // every lane holds its 16-lane-group sum
}

__global__ __launch_bounds__(NT, 2) void capsule_one(
    const float* __restrict__ inp,   // [B,R,8]
    const float* __restrict__ W,     // [O,R,128]
    float* __restrict__ out)         // [B,O,16]
{
    __shared__ float4 wbuf[CH * 32];            // 48 KB staging, XOR-swizzled
    __shared__ float4 red4[NB][NGRP][4];        // per-group s[d] partials
    __shared__ float  redS[NB][NGRP];           // per-group sum(exp)
    __shared__ __align__(16) float finalv[NB][20];

    int wg = blockIdx.x;
    wg = (wg & 7) * (GRID / 8) + (wg >> 3);     // bijective XCD swizzle
    const int o  = wg / (BB / NB);
    const int b0 = (wg % (BB / NB)) * NB;
    const int tid = threadIdx.x;
    const int g  = tid >> 4;
    const int lc = tid & 15;
    const int myphase = tid / CH;               // 0..3: which chunk-of-4 is mine
    const int rho     = tid % CH;               // my row within that chunk

    const float4* w4 = reinterpret_cast<const float4*>(W) + (size_t)o * (RR * 32);
    const float4* ip = reinterpret_cast<const float4*>(inp);

    float pri[NB][3][DD];                       // 96 floats, all registers
    #pragma unroll
    for (int nb = 0; nb < NB; ++nb)
        #pragma unroll
        for (int k = 0; k < 3; ++k)
            #pragma unroll
            for (int d = 0; d < DD; ++d) pri[nb][k][d] = 0.f;

    // ---- priors: 12 chunks; outer k unrolled so pri[][k][] is static ----
    #pragma unroll
    for (int k = 0; k < 3; ++k) {
        // hoist this k-row's input loads above the 4-chunk group (hides latency)
        const size_t rk = (size_t)(tid + k * NT);
        const float4 A0 = ip[((size_t)b0 * RR + rk) * 2];
        const float4 A1 = ip[((size_t)b0 * RR + rk) * 2 + 1];
        const float4 B0 = ip[((size_t)(b0 + 1) * RR + rk) * 2];
        const float4 B1 = ip[((size_t)(b0 + 1) * RR + rk) * 2 + 1];
        const float ain[8] = {A0.x, A0.y, A0.z, A0.w, A1.x, A1.y, A1.z, A1.w};
        const float bin[8] = {B0.x, B0.y, B0.z, B0.w, B1.x, B1.y, B1.z, B1.w};

        for (int c2 = 0; c2 < 4; ++c2) {
            const int c = k * 4 + c2;
            // stage chunk c: coalesced global, swizzled LDS write
            #pragma unroll
            for (int s = 0; s < 8; ++s) {
                const int j = tid + s * NT;               // 0..3071
                const float4 v = w4[(size_t)c * (CH * 32) + j];
                const int row = j >> 5;
                wbuf[(row * 32 + (j & 31)) ^ (row & 7)] = v;
            }
            __syncthreads();
            if (c2 == myphase) {
                // my row rho of this chunk == global route rk
                #pragma unroll
                for (int i = 0; i < II; ++i) {
                    #pragma unroll
                    for (int dq = 0; dq < 4; ++dq) {
                        const float4 w = wbuf[(rho * 32 + i * 4 + dq) ^ (rho & 7)];
                        pri[0][k][dq*4+0] = fmaf(w.x, ain[i], pri[0][k][dq*4+0]);
                        pri[0][k][dq*4+1] = fmaf(w.y, ain[i], pri[0][k][dq*4+1]);
                        pri[0][k][dq*4+2] = fmaf(w.z, ain[i], pri[0][k][dq*4+2]);
                        pri[0][k][dq*4+3] = fmaf(w.w, ain[i], pri[0][k][dq*4+3]);
                        pri[1][k][dq*4+0] = fmaf(w.x, bin[i], pri[1][k][dq*4+0]);
                        pri[1][k][dq*4+1] = fmaf(w.y, bin[i], pri[1][k][dq*4+1]);
                        pri[1][k][dq*4+2] = fmaf(w.z, bin[i], pri[1][k][dq*4+2]);
                        pri[1][k][dq*4+3] = fmaf(w.w, bin[i], pri[1][k][dq*4+3]);
                    }
                }
            }
            __syncthreads();   // before next chunk overwrites wbuf
        }
    }

    // ---- dynamic routing ----
    float lg[NB][3] = {{0.f, 0.f, 0.f}, {0.f, 0.f, 0.f}};

    #pragma unroll
    for (int it = 0; it < NITER; ++it) {
        #pragma unroll
        for (int nb = 0; nb < NB; ++nb) {
            const float e0 = __expf(lg[nb][0]);
            const float e1 = __expf(lg[nb][1]);
            const float e2 = __expf(lg[nb][2]);
            const float Sp = red16(e0 + e1 + e2);
            float4 s[4];
            #pragma unroll
            for (int dq = 0; dq < 4; ++dq) {
                float4 t;
                t.x = fmaf(e0, pri[nb][0][dq*4+0], fmaf(e1, pri[nb][1][dq*4+0], e2 * pri[nb][2][dq*4+0]));
                t.y = fmaf(e0, pri[nb][0][dq*4+1], fmaf(e1, pri[nb][1][dq*4+1], e2 * pri[nb][2][dq*4+1]));
                t.z = fmaf(e0, pri[nb][0][dq*4+2], fmaf(e1, pri[nb][1][dq*4+2], e2 * pri[nb][2][dq*4+2]));
                t.w = fmaf(e0, pri[nb][0][dq*4+3], fmaf(e1, pri[nb][1][dq*4+3], e2 * pri[nb][2][dq*4+3]));
                t.x = red16(t.x); t.y = red16(t.y); t.z = red16(t.z); t.w = red16(t.w);
                s[dq] = t;
            }
            if (lc < 4) {
                red4[nb][g][lc] = (lc & 2) ? ((lc & 1) ? s[3] : s[2])
                                           : ((lc & 1) ? s[1] : s[0]);
            } else if (lc == 4) {
                redS[nb][g] = Sp;
            }
        }
        __syncthreads();

        // cross-group reduce: 34 threads, one value each
        if (tid < 34) {
            const int nb = (tid >= 17) ? 1 : 0;
            const int j = tid - nb * 17;
            float t = 0.f;
            if (j < 16) {
                const float* base = (const float*)red4 + nb * (NGRP * 16) + j;
                #pragma unroll
                for (int gg = 0; gg < NGRP; ++gg) t += base[gg * 16];
            } else {
                #pragma unroll
                for (int gg = 0; gg < NGRP; ++gg) t += redS[nb][gg];
            }
            finalv[nb][j] = t;
        }
        __syncthreads();

        // squash + logit update / output
        #pragma unroll
        for (int nb = 0; nb < NB; ++nb) {
            const float4* fp = reinterpret_cast<const float4*>(&finalv[nb][0]);
            const float4 s0 = fp[0], s1 = fp[1], s2 = fp[2], s3 = fp[3];
            const float S = finalv[nb][16];
            const float inv = 1.0f / S;
            float sq = 0.f;
            sq = fmaf(s0.x*inv, s0.x*inv, sq); sq = fmaf(s0.y*inv, s0.y*inv, sq);
            sq = fmaf(s0.z*inv, s0.z*inv, sq); sq = fmaf(s0.w*inv, s0.w*inv, sq);
            sq = fmaf(s1.x*inv, s1.x*inv, sq); sq = fmaf(s1.y*inv, s1.y*inv, sq);
            sq = fmaf(s1.z*inv, s1.z*inv, sq); sq = fmaf(s1.w*inv, s1.w*inv, sq);
            sq = fmaf(s2.x*inv, s2.x*inv, sq); sq = fmaf(s2.y*inv, s2.y*inv, sq);
            sq = fmaf(s2.z*inv, s2.z*inv, sq); sq = fmaf(s2.w*inv, s2.w*inv, sq);
            sq = fmaf(s3.x*inv, s3.x*inv, sq); sq = fmaf(s3.y*inv, s3.y*inv, sq);
            sq = fmaf(s3.z*inv, s3.z*inv, sq); sq = fmaf(s3.w*inv, s3.w*inv, sq);
            const float F = inv * sqrtf(sq) / (1.0f + sq);   // v[d] = s[d]*F
            if (it < NITER - 1) {
                #pragma unroll
                for (int k = 0; k < 3; ++k) {
                    float d = 0.f;
                    d = fmaf(pri[nb][k][0],  s0.x, d); d = fmaf(pri[nb][k][1],  s0.y, d);
                    d = fmaf(pri[nb][k][2],  s0.z, d); d = fmaf(pri[nb][k][3],  s0.w, d);
                    d = fmaf(pri[nb][k][4],  s1.x, d); d = fmaf(pri[nb][k][5],  s1.y, d);
                    d = fmaf(pri[nb][k][6],  s1.z, d); d = fmaf(pri[nb][k][7],  s1.w, d);
                    d = fmaf(pri[nb][k][8],  s2.x, d); d = fmaf(pri[nb][k][9],  s2.y, d);
                    d = fmaf(pri[nb][k][10], s2.z, d); d = fmaf(pri[nb][k][11], s2.w, d);
                    d = fmaf(pri[nb][k][12], s3.x, d); d = fmaf(pri[nb][k][13], s3.y, d);
                    d = fmaf(pri[nb][k][14], s3.z, d); d = fmaf(pri[nb][k][15], s3.w, d);
                    lg[nb][k] = fmaf(F, d, lg[nb][k]);
                }
            } else if (tid < DD) {
                out[((size_t)(b0 + nb) * OO + o) * DD + tid] = finalv[nb][tid] * F;
            }
        }
    }
}

extern "C" void kernel_launch(void* const* d_in, const int* in_sizes, int n_in,
                              void* d_out, int out_size, void* d_ws, size_t ws_size,
                              hipStream_t stream) {
    const float* inputs = (const float*)d_in[0];
    const float* W = (const float*)d_in[1];
    float* out = (float*)d_out;
    hipLaunchKernelGGL(capsule_one, dim3(GRID), dim3(NT), 0, stream, inputs, W, out);
}